// Round 10
// baseline (206.510 us; speedup 1.0000x reference)
//
#include <hip/hip_runtime.h>
#include <hip/hip_bf16.h>

#define HID  128
#define NRAD 16
#define NT   100      // atom types (emb rows)

// Workspace: P f32 [NT][256] (102400 B) | W3 bf16 [128][128] (32768 B)
//          | Wr32 bf16 [128][32] (8192 B; col16 = b_rbf, cols 17..31 = 0)
#define WS_W3_OFF   (NT * 256 * 4)
#define WS_WR_OFF   (WS_W3_OFF + HID * HID * 2)

typedef __attribute__((ext_vector_type(4))) float f32x4;
typedef __attribute__((ext_vector_type(8))) __bf16 bf16x8;
typedef __attribute__((ext_vector_type(4))) __bf16 bf16x4;

union F8 { bf16x8 b; int4 i4; };
union B4 { bf16x4 b4; int2 i2; };

__device__ inline unsigned short f2bfbits(float f){
  unsigned int u = __float_as_uint(f);
  u += 0x7FFFu + ((u >> 16) & 1u);
  return (unsigned short)(u >> 16);
}

__device__ inline float silu_f(float v){
  return v * __builtin_amdgcn_rcpf(1.0f + __expf(-v));
}

// ---------------------------------------------------------------------------
// Setup (one launch):
//   blocks [0, ntypes)        : P[t][0:128]=emb@W1^T+b_lin ; [128:256]=emb@W2^T
//   blocks [ntypes, +64)      : W3 bf16 conversion (128x128)
//   blocks [ntypes+64, +16)   : Wr32 bf16 [128][32]: cols0-15=W_rbf, col16=b_rbf
// ---------------------------------------------------------------------------
__global__ void setup_kernel(const float* __restrict__ emb,
                             const float* __restrict__ W_lin,
                             const float* __restrict__ b_lin,
                             const float* __restrict__ W_rbf,
                             const float* __restrict__ b_rbf,
                             int ntypes,
                             float* __restrict__ P,
                             unsigned short* __restrict__ W3,
                             unsigned short* __restrict__ Wr32){
  int blk = blockIdx.x;
  int n = threadIdx.x;                // 0..255
  if (blk < ntypes){
    __shared__ float er[HID];
    if (n < HID) er[n] = emb[blk * HID + n];
    __syncthreads();
    int half = n >> 7, nn = n & 127;
    const float4* w4 = (const float4*)(W_lin + (size_t)nn * (3 * HID) + half * HID);
    float s = half ? 0.0f : b_lin[nn];
    #pragma unroll 8
    for (int k4 = 0; k4 < HID / 4; ++k4){
      float4 w = w4[k4];
      s += er[k4*4+0]*w.x + er[k4*4+1]*w.y + er[k4*4+2]*w.z + er[k4*4+3]*w.w;
    }
    P[blk * 256 + n] = s;
  } else if (blk < ntypes + 64){
    int idx = (blk - ntypes) * 256 + n;        // 0..16383
    int r = idx >> 7, k = idx & 127;
    W3[idx] = f2bfbits(W_lin[(size_t)r * (3 * HID) + 2 * HID + k]);
  } else {
    int idx = (blk - ntypes - 64) * 256 + n;   // 0..4095
    int r = idx >> 5, k = idx & 31;
    float v = (k < 16) ? W_rbf[r * NRAD + k] : (k == 16 ? b_rbf[r] : 0.f);
    Wr32[idx] = f2bfbits(v);
  }
}

// ---------------------------------------------------------------------------
// Edge kernel: 256 threads (4 waves), 64-edge tiles, grid-stride.
// SMALL LDS (16.5 KB) -> high occupancy; latency hiding via TLP.
//   phase 1: wave wv computes r = silu(rbf@Wrbf^T + b) for edges
//            [wv*16,+16) (bias via augmented k=16 column) -> swizzled LDS
//   barrier; phase 2: wave wv computes TWO n-slices (wv*16 and 64+wv*16)
//            for all 64 edges — 2 MFMAs per B ds_read (w3[8] in 32 VGPRs);
//            epilogue gathers P rows from GLOBAL (100 KB, L2-resident).
// ---------------------------------------------------------------------------
__global__ __launch_bounds__(256, 4) void edge_kernel(
    const float* __restrict__ rbf,
    const int*   __restrict__ ei,
    const int*   __restrict__ ej,
    const int*   __restrict__ x,
    const unsigned short* __restrict__ Wr32,  // bf16 [128][32]
    const float* __restrict__ Pg,             // f32 [NT][256]
    const unsigned short* __restrict__ W3,    // bf16 [128][128]
    float* __restrict__ out,
    int E, int ntile)
{
  __shared__ char rb[64 * 256];     // swizzled bf16 r-tile [64 edges][128 n]
  __shared__ int  aL[64], bL[64];

  const int tid  = threadIdx.x;
  const int lane = tid & 63;
  const int wv   = tid >> 6;        // 0..3
  const int erow = lane & 15;
  const int kgrp = lane >> 4;       // 0..3
  const int e_l  = wv * 16 + erow;  // edge-slot owned in phase 1
  const int G    = gridDim.x;

  // ---- loop-invariant register fragments ----------------------------------
  F8 wr[8];                                    // Wrbf+bias rows (phase1 A)
  #pragma unroll
  for (int t = 0; t < 8; ++t)
    wr[t].i4 = *(const int4*)(Wr32 + (t * 16 + erow) * 32 + kgrp * 8);

  F8 w3[8];                                    // W3 rows, n-tiles wv and wv+4
  #pragma unroll
  for (int u = 0; u < 2; ++u)
    #pragma unroll
    for (int s = 0; s < 4; ++s)
      w3[u*4+s].i4 = *(const int4*)(W3 + ((wv + 4*u) * 16 + erow) * HID + s * 32 + kgrp * 8);

  int tile = blockIdx.x;
  while (tile < ntile){
    const long base = (long)tile * 64;
    long ge = base + e_l; if (ge > (long)E - 1) ge = E - 1;

    // ---- index chain + rbf load (issued together; TLP hides latency) -----
    int a = 0, b = 0;
    if (kgrp == 0){
      a = x[ei[ge]];
      b = x[ej[ge]];
    }
    f32x4 f0 = {0,0,0,0}, f1 = {0,0,0,0};
    if (kgrp < 2){
      const f32x4* s4 = (const f32x4*)(rbf + ge * NRAD + kgrp * 8);
      f0 = __builtin_nontemporal_load(s4);
      f1 = __builtin_nontemporal_load(s4 + 1);
    }

    // ---- phase 1: r for own 16 edges -> swizzled LDS ----------------------
    F8 fb; fb.i4 = make_int4(0, 0, 0, 0);
    if (kgrp < 2){
      fb.b[0]=(__bf16)f0.x; fb.b[1]=(__bf16)f0.y; fb.b[2]=(__bf16)f0.z; fb.b[3]=(__bf16)f0.w;
      fb.b[4]=(__bf16)f1.x; fb.b[5]=(__bf16)f1.y; fb.b[6]=(__bf16)f1.z; fb.b[7]=(__bf16)f1.w;
    } else if (kgrp == 2){
      fb.b[0] = (__bf16)1.0f;                  // bias column (k=16)
    }
    #pragma unroll
    for (int t = 0; t < 8; ++t){
      f32x4 acc = {0.f, 0.f, 0.f, 0.f};
      acc = __builtin_amdgcn_mfma_f32_16x16x32_bf16(wr[t].b, fb.b, acc, 0, 0, 0);
      B4 pk;                                   // D: col=edge e_l, row=kgrp*4+r
      pk.b4[0] = (__bf16)silu_f(acc[0]);
      pk.b4[1] = (__bf16)silu_f(acc[1]);
      pk.b4[2] = (__bf16)silu_f(acc[2]);
      pk.b4[3] = (__bf16)silu_f(acc[3]);
      int byte = (e_l << 8) + t * 32 + kgrp * 8;
      byte ^= (e_l & 7) << 4;
      *(int2*)(rb + byte) = pk.i2;
    }
    if (kgrp == 0){ aL[e_l] = a; bL[e_l] = b; }

    asm volatile("s_waitcnt lgkmcnt(0)" ::: "memory");
    __builtin_amdgcn_s_barrier();

    // ---- phase 2 + epilogue: n-slices wv*16 and 64+wv*16, all 64 edges ----
    #pragma unroll
    for (int eg = 0; eg < 4; ++eg){
      const int ed = eg * 16 + erow;
      f32x4 a0 = {0.f,0.f,0.f,0.f}, a1 = {0.f,0.f,0.f,0.f};
      #pragma unroll
      for (int s = 0; s < 4; ++s){
        int byte = (ed << 8) + s * 64 + kgrp * 16;
        byte ^= (ed & 7) << 4;
        F8 bB; bB.i4 = *(const int4*)(rb + byte);   // B: col=edge ed
        a0 = __builtin_amdgcn_mfma_f32_16x16x32_bf16(w3[s].b,   bB.b, a0, 0, 0, 0);
        a1 = __builtin_amdgcn_mfma_f32_16x16x32_bf16(w3[4+s].b, bB.b, a1, 0, 0, 0);
      }
      const int aT = aL[ed], bT = bL[ed];
      const long go = base + ed;
      #pragma unroll
      for (int u = 0; u < 2; ++u){
        f32x4 acc = u ? a1 : a0;
        const int nb = (wv + 4*u) * 16 + kgrp * 4;
        f32x4 p1 = *(const f32x4*)(Pg + aT * 256 + nb);
        f32x4 p2 = *(const f32x4*)(Pg + bT * 256 + 128 + nb);
        f32x4 o;
        o.x = silu_f(acc[0] + p1.x + p2.x);
        o.y = silu_f(acc[1] + p1.y + p2.y);
        o.z = silu_f(acc[2] + p1.z + p2.z);
        o.w = silu_f(acc[3] + p1.w + p2.w);
        if (go < E)
          *(f32x4*)(out + go * HID + nb) = o;
      }
    }

    __builtin_amdgcn_s_barrier();              // WAR: rb/aL reused next tile
    tile += G;
  }
}

// ---------------------------------------------------------------------------
extern "C" void kernel_launch(void* const* d_in, const int* in_sizes, int n_in,
                              void* d_out, int out_size, void* d_ws, size_t ws_size,
                              hipStream_t stream){
  const int*   x    = (const int*)  d_in[0];
  const float* rbf  = (const float*)d_in[1];
  const int*   ei   = (const int*)  d_in[2];
  const int*   ej   = (const int*)  d_in[3];
  const float* emb  = (const float*)d_in[4];
  const float* Wrbf = (const float*)d_in[5];
  const float* brbf = (const float*)d_in[6];
  const float* Wlin = (const float*)d_in[7];
  const float* blin = (const float*)d_in[8];
  float* out = (float*)d_out;

  const int E      = in_sizes[2];
  const int ntypes = in_sizes[4] / HID;   // 100

  float*          P    = (float*)d_ws;
  unsigned short* W3   = (unsigned short*)((char*)d_ws + WS_W3_OFF);
  unsigned short* Wr32 = (unsigned short*)((char*)d_ws + WS_WR_OFF);

  setup_kernel<<<ntypes + 64 + 16, 256, 0, stream>>>(
      emb, Wlin, blin, Wrbf, brbf, ntypes, P, W3, Wr32);

  const int ntile = (E + 63) / 64;
  const int nblk  = ntile < 2048 ? ntile : 2048;
  edge_kernel<<<nblk, 256, 0, stream>>>(
      rbf, ei, ej, x, Wr32, P, W3, out, E, ntile);
}

// Round 11
// 158.246 us; speedup vs baseline: 1.3050x; 1.3050x over previous
//
#include <hip/hip_runtime.h>
#include <hip/hip_bf16.h>

#define HID  128
#define NRAD 16
#define NT   100      // atom types (emb rows)
#define TE   96       // edges per tile

// LDS (dynamic, 77344 B -> 2 blocks/CU):
//   Pl : bf16 [NT][260] (padded rows -> bank rotation)   52000 B
//   rb : [96 edges][256 B] swizzled bf16 r-tile          24576 B
//   aL,bL : [96] int                                       768 B
#define PL_BYTES   (NT * 260 * 2)
#define RB_OFF     PL_BYTES
#define AL_OFF     (RB_OFF + TE * 256)
#define BL_OFF     (AL_OFF + TE * 4)
#define LDS_BYTES  (BL_OFF + TE * 4)

// Workspace: Pbf bf16 [NT][260] | W3 bf16 [128][128] | Wr32 bf16 [128][32]
#define WS_W3_OFF   PL_BYTES
#define WS_WR_OFF   (WS_W3_OFF + HID * HID * 2)

typedef __attribute__((ext_vector_type(4))) float f32x4;
typedef __attribute__((ext_vector_type(8))) __bf16 bf16x8;
typedef __attribute__((ext_vector_type(4))) __bf16 bf16x4;

union F8 { bf16x8 b; int4 i4; };
union B4 { bf16x4 b4; int2 i2; };

__device__ inline unsigned short f2bfbits(float f){
  unsigned int u = __float_as_uint(f);
  u += 0x7FFFu + ((u >> 16) & 1u);
  return (unsigned short)(u >> 16);
}

__device__ inline float silu_f(float v){
  return v * __builtin_amdgcn_rcpf(1.0f + __expf(-v));
}

__device__ inline float bflo(int q){ return __uint_as_float((unsigned)q << 16); }
__device__ inline float bfhi(int q){ return __uint_as_float((unsigned)q & 0xFFFF0000u); }

// ---------------------------------------------------------------------------
// Setup (one launch):
//   blocks [0, ntypes)      : Pbf[t][0:128]=emb@W1^T+b_lin ; [128:256]=emb@W2^T
//   blocks [ntypes, +64)    : W3 bf16 (128x128)
//   blocks [ntypes+64, +16) : Wr32 bf16 [128][32]: cols0-15=W_rbf, col16=b_rbf
// ---------------------------------------------------------------------------
__global__ void setup_kernel(const float* __restrict__ emb,
                             const float* __restrict__ W_lin,
                             const float* __restrict__ b_lin,
                             const float* __restrict__ W_rbf,
                             const float* __restrict__ b_rbf,
                             int ntypes,
                             unsigned short* __restrict__ Pbf,
                             unsigned short* __restrict__ W3,
                             unsigned short* __restrict__ Wr32){
  int blk = blockIdx.x;
  int n = threadIdx.x;                // 0..255
  if (blk < ntypes){
    __shared__ float er[HID];
    if (n < HID) er[n] = emb[blk * HID + n];
    __syncthreads();
    int half = n >> 7, nn = n & 127;
    const float4* w4 = (const float4*)(W_lin + (size_t)nn * (3 * HID) + half * HID);
    float s = half ? 0.0f : b_lin[nn];
    #pragma unroll 8
    for (int k4 = 0; k4 < HID / 4; ++k4){
      float4 w = w4[k4];
      s += er[k4*4+0]*w.x + er[k4*4+1]*w.y + er[k4*4+2]*w.z + er[k4*4+3]*w.w;
    }
    Pbf[blk * 260 + n] = f2bfbits(s);
    if (n < 4) Pbf[blk * 260 + 256 + n] = 0;   // deterministic pad
  } else if (blk < ntypes + 64){
    int idx = (blk - ntypes) * 256 + n;        // 0..16383
    int r = idx >> 7, k = idx & 127;
    W3[idx] = f2bfbits(W_lin[(size_t)r * (3 * HID) + 2 * HID + k]);
  } else {
    int idx = (blk - ntypes - 64) * 256 + n;   // 0..4095
    int r = idx >> 5, k = idx & 31;
    float v = (k < 16) ? W_rbf[r * NRAD + k] : (k == 16 ? b_rbf[r] : 0.f);
    Wr32[idx] = f2bfbits(v);
  }
}

// ---------------------------------------------------------------------------
// Edge kernel: 512 threads (8 waves), 96-edge tiles, grid-stride.
// 77.3 KB LDS -> 2 blocks/CU (16 waves/CU, 4 waves/SIMD): barrier intervals
// of the two blocks overlap, doubling latency hiding vs the 136 KB variant.
//   phase 1: waves 0..5 compute r = silu(rbf@Wrbf^T + b) for their 16 edges
//            (bias via augmented k=16 column) -> swizzled LDS
//   barrier; phase 2: all 8 waves: n-slice [wv*16,+16) for all 96 edges,
//            P gathered from bf16 LDS table; barrier.
// ---------------------------------------------------------------------------
__global__ __launch_bounds__(512, 4) void edge_kernel(
    const float* __restrict__ rbf,
    const int*   __restrict__ ei,
    const int*   __restrict__ ej,
    const int*   __restrict__ x,
    const unsigned short* __restrict__ Wr32,  // bf16 [128][32]
    const unsigned short* __restrict__ Pbf,   // bf16 [NT][260]
    const unsigned short* __restrict__ W3,    // bf16 [128][128]
    float* __restrict__ out,
    int E, int ntile)
{
  extern __shared__ char smem[];
  char* rb = smem + RB_OFF;
  int*  aL = (int*)(smem + AL_OFF);
  int*  bL = (int*)(smem + BL_OFF);

  const int tid  = threadIdx.x;
  const int lane = tid & 63;
  const int wv   = tid >> 6;        // 0..7
  const int erow = lane & 15;
  const int kgrp = lane >> 4;       // 0..3
  const int e_l  = wv * 16 + erow;  // phase-1 edge slot (valid for wv<6)
  const int G    = gridDim.x;

  // ---- stage Pbf into LDS -------------------------------------------------
  for (int i = tid; i < PL_BYTES / 16; i += 512)
    ((int4*)smem)[i] = ((const int4*)Pbf)[i];

  // ---- loop-invariant register fragments ----------------------------------
  F8 wr[8];                                    // Wrbf+bias rows (phase1 A)
  #pragma unroll
  for (int t = 0; t < 8; ++t)
    wr[t].i4 = *(const int4*)(Wr32 + (t * 16 + erow) * 32 + kgrp * 8);

  F8 w3[4];                                    // W3 rows for n-tile wv
  #pragma unroll
  for (int s = 0; s < 4; ++s)
    w3[s].i4 = *(const int4*)(W3 + (wv * 16 + erow) * HID + s * 32 + kgrp * 8);

  // ---- prologue: first tile's rbf -----------------------------------------
  int tile = blockIdx.x;
  f32x4 f0 = {0,0,0,0}, f1 = {0,0,0,0};
  if (wv < 6 && kgrp < 2 && tile < ntile){
    long ge = (long)tile * TE + e_l; if (ge > (long)E - 1) ge = E - 1;
    const f32x4* s4 = (const f32x4*)(rbf + ge * NRAD + kgrp * 8);
    f0 = __builtin_nontemporal_load(s4);
    f1 = __builtin_nontemporal_load(s4 + 1);
  }

  __syncthreads();                             // P staged

  while (tile < ntile){
    const long base = (long)tile * TE;
    const int  next = tile + G;

    // ---- x-gather chain for CURRENT tile (threads 0..95) ------------------
    int a = 0, b = 0;
    if (tid < TE){
      long ge = base + tid; if (ge > (long)E - 1) ge = E - 1;
      a = x[ei[ge]];
      b = x[ej[ge]];
    }

    // ---- prefetch next tile's rbf -----------------------------------------
    f32x4 nf0 = {0,0,0,0}, nf1 = {0,0,0,0};
    if (wv < 6 && kgrp < 2 && next < ntile){
      long gn = (long)next * TE + e_l; if (gn > (long)E - 1) gn = E - 1;
      const f32x4* s4 = (const f32x4*)(rbf + gn * NRAD + kgrp * 8);
      nf0 = __builtin_nontemporal_load(s4);
      nf1 = __builtin_nontemporal_load(s4 + 1);
    }

    // ---- phase 1: waves 0..5 compute r for their 16 edges -----------------
    if (wv < 6){
      F8 fb; fb.i4 = make_int4(0, 0, 0, 0);
      if (kgrp < 2){
        fb.b[0]=(__bf16)f0.x; fb.b[1]=(__bf16)f0.y; fb.b[2]=(__bf16)f0.z; fb.b[3]=(__bf16)f0.w;
        fb.b[4]=(__bf16)f1.x; fb.b[5]=(__bf16)f1.y; fb.b[6]=(__bf16)f1.z; fb.b[7]=(__bf16)f1.w;
      } else if (kgrp == 2){
        fb.b[0] = (__bf16)1.0f;                // bias column (k=16)
      }
      #pragma unroll
      for (int t = 0; t < 8; ++t){
        f32x4 acc = {0.f, 0.f, 0.f, 0.f};
        acc = __builtin_amdgcn_mfma_f32_16x16x32_bf16(wr[t].b, fb.b, acc, 0, 0, 0);
        B4 pk;                                 // D: col=edge e_l, row=kgrp*4+r
        pk.b4[0] = (__bf16)silu_f(acc[0]);
        pk.b4[1] = (__bf16)silu_f(acc[1]);
        pk.b4[2] = (__bf16)silu_f(acc[2]);
        pk.b4[3] = (__bf16)silu_f(acc[3]);
        int byte = (e_l << 8) + t * 32 + kgrp * 8;
        byte ^= (e_l & 7) << 4;
        *(int2*)(rb + byte) = pk.i2;
      }
    }
    if (tid < TE){ aL[tid] = a; bL[tid] = b; }

    asm volatile("s_waitcnt lgkmcnt(0)" ::: "memory");
    __builtin_amdgcn_s_barrier();

    // ---- phase 2 + epilogue: n-slice [wv*16,+16) for all 96 edges ---------
    const int nb = wv * 16 + kgrp * 4;
    const unsigned short* PlU = (const unsigned short*)smem;
    #pragma unroll
    for (int eg = 0; eg < 6; ++eg){
      const int ed = eg * 16 + erow;
      f32x4 acc = {0.f, 0.f, 0.f, 0.f};
      #pragma unroll
      for (int s = 0; s < 4; ++s){
        int byte = (ed << 8) + s * 64 + kgrp * 16;
        byte ^= (ed & 7) << 4;
        F8 bB; bB.i4 = *(const int4*)(rb + byte);   // B: col=edge ed
        acc = __builtin_amdgcn_mfma_f32_16x16x32_bf16(w3[s].b, bB.b, acc, 0, 0, 0);
      }
      const int aT = aL[ed], bT = bL[ed];
      int2 q1 = *(const int2*)(PlU + aT * 260 + nb);
      int2 q2 = *(const int2*)(PlU + bT * 260 + 128 + nb);
      f32x4 o;
      o.x = silu_f(acc[0] + bflo(q1.x) + bflo(q2.x));
      o.y = silu_f(acc[1] + bfhi(q1.x) + bfhi(q2.x));
      o.z = silu_f(acc[2] + bflo(q1.y) + bflo(q2.y));
      o.w = silu_f(acc[3] + bfhi(q1.y) + bfhi(q2.y));
      long go = base + ed;
      if (go < E)
        *(f32x4*)(out + go * HID + nb) = o;
    }

    __builtin_amdgcn_s_barrier();              // WAR: rb/aL/bL reused next tile

    f0 = nf0; f1 = nf1;
    tile = next;
  }
}

// ---------------------------------------------------------------------------
extern "C" void kernel_launch(void* const* d_in, const int* in_sizes, int n_in,
                              void* d_out, int out_size, void* d_ws, size_t ws_size,
                              hipStream_t stream){
  const int*   x    = (const int*)  d_in[0];
  const float* rbf  = (const float*)d_in[1];
  const int*   ei   = (const int*)  d_in[2];
  const int*   ej   = (const int*)  d_in[3];
  const float* emb  = (const float*)d_in[4];
  const float* Wrbf = (const float*)d_in[5];
  const float* brbf = (const float*)d_in[6];
  const float* Wlin = (const float*)d_in[7];
  const float* blin = (const float*)d_in[8];
  float* out = (float*)d_out;

  const int E      = in_sizes[2];
  const int ntypes = in_sizes[4] / HID;   // 100

  unsigned short* Pbf  = (unsigned short*)d_ws;
  unsigned short* W3   = (unsigned short*)((char*)d_ws + WS_W3_OFF);
  unsigned short* Wr32 = (unsigned short*)((char*)d_ws + WS_WR_OFF);

  setup_kernel<<<ntypes + 64 + 16, 256, 0, stream>>>(
      emb, Wlin, blin, Wrbf, brbf, ntypes, Pbf, W3, Wr32);

  (void)hipFuncSetAttribute(reinterpret_cast<const void*>(&edge_kernel),
                            hipFuncAttributeMaxDynamicSharedMemorySize, LDS_BYTES);

  const int ntile = (E + TE - 1) / TE;
  const int nblk  = ntile < 512 ? ntile : 512;
  edge_kernel<<<nblk, 512, LDS_BYTES, stream>>>(
      rbf, ei, ej, x, Wr32, Pbf, W3, out, E, ntile);
}